// Round 5
// baseline (183.694 us; speedup 1.0000x reference)
//
#include <hip/hip_runtime.h>

#define NN 50000
#define NE 100000
#define IN_F 63
#define HID 64
#define NREL 8
#define CHUNK 64

// ---- kernel 1: sender degree + receiver linked-list build -----------------
__global__ __launch_bounds__(256) void deg_link_kernel(const int* __restrict__ senders,
                                                       const int* __restrict__ receivers,
                                                       float* __restrict__ sdeg,
                                                       int* __restrict__ head,
                                                       int* __restrict__ nxt) {
    int e = blockIdx.x * 256 + threadIdx.x;
    if (e < NE) {
        atomicAdd(&sdeg[senders[e]], 1.0f);
        // receiver-bucket linked list: head[r] -> e -> old chain
        int old = atomicExch(&head[receivers[e]], e);
        nxt[e] = old;
    }
}

// ---- kernel 2: per-edge messages, PLAIN stores (no scatter atomics) -------
// Wave = (64-edge chunk, relation t). Lane f holds K[t][0..63][f] pinned in
// VGPRs (kcol[63]=0 pads the row so the FMA loop is a clean 16x float4).
// Round-4 evidence: scatter atomicAdds (6.4M 4B RMW ops) were the ~43us
// bottleneck at ~1 atomic/cyc/channel. Messages now go to M[e] with one
// coalesced 256B plain store per edge; a gather kernel sums them.
__global__ __launch_bounds__(256, 4) void msg_kernel(const float* __restrict__ nodes,
                                                     const int* __restrict__ senders,
                                                     const int* __restrict__ etypes,
                                                     const float* __restrict__ kernels,
                                                     const float* __restrict__ sdeg,
                                                     float* __restrict__ M) {
    const int lane = threadIdx.x & 63;
    const int t = blockIdx.x & (NREL - 1);
    const int chunk = (blockIdx.x >> 3) * 4 + (threadIdx.x >> 6);
    const int base = chunk * CHUNK;
    if (base >= NE) return;
    const int lim = min(base + CHUNK, NE);

    // relation column in registers, padded to 64 (kcol[63] = 0)
    float kcol[HID];
    const float* Kt = kernels + (size_t)t * IN_F * HID;
#pragma unroll
    for (int i = 0; i < IN_F; ++i) kcol[i] = Kt[i * HID + lane];
    kcol[IN_F] = 0.0f;
#pragma unroll
    for (int i = 0; i < HID; ++i) asm volatile("" : "+v"(kcol[i]));

    // cooperative metadata preload for the 64-edge chunk
    const int e = base + lane;
    int s_l = 0, ty = -1;
    if (e < lim) {
        ty  = etypes[e];
        s_l = senders[e];
    }
    float ns_l = 1.0f;
    if (ty == t) ns_l = rsqrtf(fmaxf(sdeg[s_l], 1.0f));

    unsigned long long m = __ballot(ty == t);
    while (m) {
        const int i0 = __builtin_ctzll(m); m &= m - 1;
        const bool has2 = (m != 0);
        const int i1 = has2 ? __builtin_ctzll(m) : i0;
        if (has2) m &= m - 1;

        const int   s0  = __builtin_amdgcn_readfirstlane(__shfl(s_l, i0));
        const float ns0 = __shfl(ns_l, i0);
        const int   s1  = __builtin_amdgcn_readfirstlane(__shfl(s_l, i1));
        const float ns1 = __shfl(ns_l, i1);
        const int e0 = base + i0, e1 = base + i1;

        const float4* xa = (const float4*)(nodes + (size_t)s0 * HID);
        const float4* xb = (const float4*)(nodes + (size_t)s1 * HID);
        float a0 = 0.f, a1 = 0.f, a2 = 0.f, a3 = 0.f;
        float b0 = 0.f, b1 = 0.f, b2 = 0.f, b3 = 0.f;
#pragma unroll
        for (int j = 0; j < 16; ++j) {
            const float4 va = xa[j];
            const float4 vb = xb[j];
            a0 = fmaf(kcol[4 * j + 0], va.x, a0);
            a1 = fmaf(kcol[4 * j + 1], va.y, a1);
            a2 = fmaf(kcol[4 * j + 2], va.z, a2);
            a3 = fmaf(kcol[4 * j + 3], va.w, a3);   // kcol[63]=0 kills root slot
            b0 = fmaf(kcol[4 * j + 0], vb.x, b0);
            b1 = fmaf(kcol[4 * j + 1], vb.y, b1);
            b2 = fmaf(kcol[4 * j + 2], vb.z, b2);
            b3 = fmaf(kcol[4 * j + 3], vb.w, b3);
        }
        M[(size_t)e0 * HID + lane] = ((a0 + a1) + (a2 + a3)) * ns0;
        if (has2)
            M[(size_t)e1 * HID + lane] = ((b0 + b1) + (b2 + b3)) * ns1;
    }
}

// ---- kernel 3: gather + relu + root-weighted readout ----------------------
// Per node: walk the receiver list (avg depth 2), sum message rows, degree =
// list length (free), then relu(acc*nr)*root*w[f], wave+block reduce, one
// atomicAdd(out) per block.
__global__ __launch_bounds__(256) void gather_kernel(const float* __restrict__ nodes,
                                                     const float* __restrict__ M,
                                                     const int* __restrict__ head,
                                                     const int* __restrict__ nxt,
                                                     const float* __restrict__ w,
                                                     const float* __restrict__ b,
                                                     float* __restrict__ out) {
    __shared__ float bsum;
    if (threadIdx.x == 0) bsum = 0.f;
    __syncthreads();

    const int lane = threadIdx.x & 63;
    const int gw = blockIdx.x * 4 + (threadIdx.x >> 6);
    const int nw = gridDim.x * 4;
    const float wf = w[lane];

    float part = 0.f;
    for (int n = gw; n < NN; n += nw) {
        int p = head[n];                            // wave-uniform
        float acc = 0.f, deg = 0.f;
        while (p >= 0) {
            const int pn = nxt[p];                  // issue chase first
            acc += M[(size_t)p * HID + lane];       // coalesced 256B
            deg += 1.f;
            p = pn;
        }
        const float nr = rsqrtf(fmaxf(deg, 1.0f));
        const float root = nodes[(size_t)n * HID + IN_F];
        part += fmaxf(acc * nr, 0.f) * root;
    }
    float v = part * wf;
#pragma unroll
    for (int o = 32; o > 0; o >>= 1) v += __shfl_xor(v, o, 64);

    if (lane == 0) atomicAdd(&bsum, v);
    __syncthreads();
    if (threadIdx.x == 0) {
        float val = bsum;
        if (blockIdx.x == 0) val += b[0];
        atomicAdd(out, val);
    }
}

extern "C" void kernel_launch(void* const* d_in, const int* in_sizes, int n_in,
                              void* d_out, int out_size, void* d_ws, size_t ws_size,
                              hipStream_t stream) {
    const float* nodes     = (const float*)d_in[0];
    const int*   senders   = (const int*)d_in[1];
    const int*   receivers = (const int*)d_in[2];
    const int*   etypes    = (const int*)d_in[3];
    // d_in[4] = n_node (single graph; unused)
    const float* kernels   = (const float*)d_in[5];
    const float* dense_w   = (const float*)d_in[6];
    const float* dense_b   = (const float*)d_in[7];
    float* out = (float*)d_out;

    // workspace layout
    float* M    = (float*)d_ws;                       // NE x HID  (25.6 MB, no init needed)
    int*   head = (int*)(M + (size_t)NE * HID);       // NN
    int*   nxt  = head + NN;                          // NE
    float* sdeg = (float*)(nxt + NE);                 // NN

    hipMemsetAsync(head, 0xFF, NN * sizeof(int), stream);       // -1 sentinels
    hipMemsetAsync(sdeg, 0, NN * sizeof(float), stream);
    hipMemsetAsync(d_out, 0, sizeof(float), stream);

    deg_link_kernel<<<(NE + 255) / 256, 256, 0, stream>>>(senders, receivers,
                                                          sdeg, head, nxt);

    const int nchunks = (NE + CHUNK - 1) / CHUNK;          // 1563
    const int cgroups = (nchunks + 3) / 4;                 // 391
    const int blocks  = cgroups * NREL;                    // 3128
    msg_kernel<<<blocks, 256, 0, stream>>>(nodes, senders, etypes,
                                           kernels, sdeg, M);

    gather_kernel<<<2048, 256, 0, stream>>>(nodes, M, head, nxt,
                                            dense_w, dense_b, out);
}

// Round 7
// 124.333 us; speedup vs baseline: 1.4774x; 1.4774x over previous
//
#include <hip/hip_runtime.h>

#define NN 50000
#define NE 100000
#define IN_F 63
#define HID 64
#define NREL 8
#define CHUNK 64
#define R1_BLOCKS 2048

// ---------------- degree kernel: float histograms of senders/receivers ----
__global__ __launch_bounds__(256) void deg_kernel(const int* __restrict__ senders,
                                                  const int* __restrict__ receivers,
                                                  float* __restrict__ sdeg,
                                                  float* __restrict__ rdeg) {
    int e = blockIdx.x * 256 + threadIdx.x;
    if (e < NE) {
        atomicAdd(&sdeg[senders[e]], 1.0f);
        atomicAdd(&rdeg[receivers[e]], 1.0f);
    }
}

// ---------------- edge kernel (round-4 proven form) ------------------------
// Wave = (64-edge chunk, relation t); lane = feature. kcol in registers
// (pin asm dropped — measured neutral r2 vs r4). Ballot-scan for matching
// edges, 2 edges/iter with 4 rotating accumulators each, one coalesced
// 256B atomicAdd burst per edge into agg[receiver].
__global__ __launch_bounds__(256) void edge_kernel(const float* __restrict__ nodes,
                                                   const int* __restrict__ senders,
                                                   const int* __restrict__ receivers,
                                                   const int* __restrict__ etypes,
                                                   const float* __restrict__ kernels,
                                                   const float* __restrict__ sdeg,
                                                   float* __restrict__ agg) {
    const int lane = threadIdx.x & 63;
    const int t = blockIdx.x & (NREL - 1);
    const int chunk = (blockIdx.x >> 3) * 4 + (threadIdx.x >> 6);
    const int base = chunk * CHUNK;
    if (base >= NE) return;
    const int lim = min(base + CHUNK, NE);

    float kcol[IN_F];
    const float* Kt = kernels + (size_t)t * IN_F * HID;
#pragma unroll
    for (int i = 0; i < IN_F; ++i) kcol[i] = Kt[i * HID + lane];

    const int e = base + lane;
    int pack_l = 0, ty = -1, s_tmp = 0;
    if (e < lim) {
        ty     = etypes[e];
        s_tmp  = senders[e];
        pack_l = s_tmp | (receivers[e] << 16);
    }
    float ns_l = 1.0f;
    if (ty == t) ns_l = rsqrtf(fmaxf(sdeg[s_tmp], 1.0f));

    unsigned long long m = __ballot(ty == t);
    while (m) {
        const int i0 = __builtin_ctzll(m); m &= m - 1;
        const bool has2 = (m != 0);
        const int i1 = has2 ? __builtin_ctzll(m) : i0;
        if (has2) m &= m - 1;

        const int   p0  = __builtin_amdgcn_readfirstlane(__shfl(pack_l, i0));
        const float ns0 = __shfl(ns_l, i0);
        const int   p1  = __builtin_amdgcn_readfirstlane(__shfl(pack_l, i1));
        const float ns1 = __shfl(ns_l, i1);
        const int s0 = p0 & 0xFFFF, r0 = ((unsigned)p0) >> 16;
        const int s1 = p1 & 0xFFFF, r1 = ((unsigned)p1) >> 16;

        const float4* xa = (const float4*)(nodes + (size_t)s0 * (IN_F + 1));
        const float4* xb = (const float4*)(nodes + (size_t)s1 * (IN_F + 1));
        float a0 = 0.f, a1 = 0.f, a2 = 0.f, a3 = 0.f;
        float b0 = 0.f, b1 = 0.f, b2 = 0.f, b3 = 0.f;
#pragma unroll
        for (int j = 0; j < 16; ++j) {
            const float4 va = xa[j];
            const float4 vb = xb[j];
            a0 = fmaf(kcol[4 * j + 0], va.x, a0);
            a1 = fmaf(kcol[4 * j + 1], va.y, a1);
            a2 = fmaf(kcol[4 * j + 2], va.z, a2);
            if (4 * j + 3 < IN_F) a3 = fmaf(kcol[4 * j + 3], va.w, a3);
            b0 = fmaf(kcol[4 * j + 0], vb.x, b0);
            b1 = fmaf(kcol[4 * j + 1], vb.y, b1);
            b2 = fmaf(kcol[4 * j + 2], vb.z, b2);
            if (4 * j + 3 < IN_F) b3 = fmaf(kcol[4 * j + 3], vb.w, b3);
        }
        atomicAdd(&agg[(size_t)r0 * HID + lane], ((a0 + a1) + (a2 + a3)) * ns0);
        if (has2)
            atomicAdd(&agg[(size_t)r1 * HID + lane], ((b0 + b1) + (b2 + b3)) * ns1);
    }
}

// ---- readout stage 1: per-block partial, PLAIN store (no contended atomics)
// Round-6 theory: 1024 blocks atomicAdd-ing the same 4B `out` address (plus
// LDS atomics) serialize at one TCC slice — removable. Each block reduces via
// shfl + LDS tree and plain-stores partial[blockIdx].
__global__ __launch_bounds__(256) void readout1_kernel(const float* __restrict__ nodes,
                                                       const float* __restrict__ agg,
                                                       const float* __restrict__ rdeg,
                                                       const float* __restrict__ w,
                                                       float* __restrict__ partial) {
    __shared__ float wsum[4];
    const int lane = threadIdx.x & 63;
    const int wid  = threadIdx.x >> 6;
    const int gw = blockIdx.x * 4 + wid;
    const int nw = R1_BLOCKS * 4;
    const float wf = w[lane];

    float local = 0.f;
    for (int n = gw; n < NN; n += nw) {
        float a = agg[(size_t)n * HID + lane];
        float nr = rsqrtf(fmaxf(rdeg[n], 1.0f));
        float root = nodes[(size_t)n * (IN_F + 1) + IN_F];  // wave-uniform
        local += fmaxf(a * nr, 0.f) * root;
    }
    float v = local * wf;
#pragma unroll
    for (int o = 32; o > 0; o >>= 1) v += __shfl_xor(v, o, 64);
    if (lane == 0) wsum[wid] = v;
    __syncthreads();
    if (threadIdx.x == 0)
        partial[blockIdx.x] = (wsum[0] + wsum[1]) + (wsum[2] + wsum[3]);
}

// ---- readout stage 2: one block sums partials + bias, plain store ---------
__global__ __launch_bounds__(256) void readout2_kernel(const float* __restrict__ partial,
                                                       const float* __restrict__ b,
                                                       float* __restrict__ out) {
    __shared__ float wsum[4];
    const int lane = threadIdx.x & 63;
    const int wid  = threadIdx.x >> 6;
    float v = 0.f;
    for (int i = threadIdx.x; i < R1_BLOCKS; i += 256) v += partial[i];
#pragma unroll
    for (int o = 32; o > 0; o >>= 1) v += __shfl_xor(v, o, 64);
    if (lane == 0) wsum[wid] = v;
    __syncthreads();
    if (threadIdx.x == 0)
        out[0] = (wsum[0] + wsum[1]) + (wsum[2] + wsum[3]) + b[0];
}

extern "C" void kernel_launch(void* const* d_in, const int* in_sizes, int n_in,
                              void* d_out, int out_size, void* d_ws, size_t ws_size,
                              hipStream_t stream) {
    const float* nodes     = (const float*)d_in[0];
    const int*   senders   = (const int*)d_in[1];
    const int*   receivers = (const int*)d_in[2];
    const int*   etypes    = (const int*)d_in[3];
    // d_in[4] = n_node (single graph; unused)
    const float* kernels   = (const float*)d_in[5];
    const float* dense_w   = (const float*)d_in[6];
    const float* dense_b   = (const float*)d_in[7];
    float* out = (float*)d_out;

    float* agg     = (float*)d_ws;                  // NN x HID
    float* sdeg    = agg + (size_t)NN * HID;        // NN
    float* rdeg    = sdeg + NN;                     // NN
    float* partial = rdeg + NN;                     // R1_BLOCKS

    size_t zero_bytes = ((size_t)NN * HID + 2 * (size_t)NN) * sizeof(float);
    (void)hipMemsetAsync(d_ws, 0, zero_bytes, stream);

    deg_kernel<<<(NE + 255) / 256, 256, 0, stream>>>(senders, receivers, sdeg, rdeg);

    const int nchunks = (NE + CHUNK - 1) / CHUNK;          // 1563
    const int cgroups = (nchunks + 3) / 4;                 // 391
    const int blocks  = cgroups * NREL;                    // 3128
    edge_kernel<<<blocks, 256, 0, stream>>>(nodes, senders, receivers, etypes,
                                            kernels, sdeg, agg);

    readout1_kernel<<<R1_BLOCKS, 256, 0, stream>>>(nodes, agg, rdeg, dense_w, partial);
    readout2_kernel<<<1, 256, 0, stream>>>(partial, dense_b, out);
}